// Round 6
// baseline (330.321 us; speedup 1.0000x reference)
//
#include <hip/hip_runtime.h>

// ZeroWeave: x[B,C,64,64] -> out[B,C,190,190], out[:,:,::3,::3]=x, rest 0.
// B=32, C=64, num_zeros=2 (s=3). out = 295.7 MB (harness poisons d_out every
// timed call -> must write all of it), x = 33.5 MB. Floor ~52 us @ 6.3 TB/s.
//
// R1-R4 post-mortem: four structurally different kernels (per-element decode,
// float2/thread, plane-block + LDS, branchless table compose) ALL land at
// ~125-128 us kernel time (~2.6 TB/s), while per-pipe arithmetic (VALU ~5 us,
// LDS ~14 us, store data ~52 us) says 55-60 us. The only shared trait was
// DEFAULT stores. Hypothesis: L2 write-allocate fetches lines from HBM on
// store miss (RFO): 296 wr + 296 RFO + 34 rd = 626 MB ~= 100+ us -- matches.
// The rocclr fill (6.3 TB/s, FETCH_SIZE ~0) uses a no-allocate store path.
//
// R5: all output stores nontemporal (nt flag, no L2 allocate / no RFO); x
// staging loads nontemporal too. R5b: use clang ext_vector_type instead of
// HIP float4 — __builtin_nontemporal_* rejects class types.
//
// Pattern: 6 output rows = 1140 floats = exactly 285 float4 (16B-aligned
// groups of 4560 B). Plane = 9025 float4 = 31 full groups + 190-float4
// partial (pattern rows 0..3 -> reuses table entries 0..189).
//
// Exact magic divs (range-verified):
//   e/190 = (e*44151)>>23  exact for e < 102300 (used e < 1140)
//   n/3   = (n*171)>>9     exact for n < 512    (used n < 190)
//   q/285 = (q*58868)>>24  exact for q <= 9024

typedef float vfloat4 __attribute__((ext_vector_type(4)));

constexpr int PLANE_IN   = 64 * 64;          // 4096 floats = 16 KB
constexpr int PLANE_OUT4 = 190 * 190 / 4;    // 9025 float4
constexpr int GROUP4     = 285;              // float4 per 6-row group
constexpr int NPLANES    = 32 * 64;          // 2048
constexpr int BLOCK      = 256;
constexpr int FULL_ITERS = PLANE_OUT4 / BLOCK;              // 35
constexpr int TAIL       = PLANE_OUT4 - FULL_ITERS * BLOCK; // 65

__global__ __launch_bounds__(BLOCK) void ZeroWeave_89601607729830_kernel(
    const float* __restrict__ x, float* __restrict__ out) {
    __shared__ float    xs[PLANE_IN];
    __shared__ unsigned tab[GROUP4];

    const int bc = blockIdx.x;
    const int t  = threadIdx.x;

    // Stage x plane -> LDS (1024 x 16B, coalesced, nontemporal).
    {
        const vfloat4* xp = reinterpret_cast<const vfloat4*>(x + bc * PLANE_IN);
        vfloat4* xl = reinterpret_cast<vfloat4*>(xs);
#pragma unroll
        for (int k = 0; k < PLANE_IN / 4 / BLOCK; ++k)
            xl[k * BLOCK + t] = __builtin_nontemporal_load(xp + k * BLOCK + t);
    }

    // Build the 285-entry pattern table (once per block, ~free).
    for (int p = t; p < GROUP4; p += BLOCK) {
        unsigned packed = 0;
#pragma unroll
        for (int j = 0; j < 4; ++j) {
            unsigned e  = 4u * p + j;              // element within group, <1140
            unsigned h  = (e * 44151u) >> 23;      // e / 190 (pattern row 0..5)
            unsigned w  = e - h * 190u;
            unsigned h3 = (h * 171u) >> 9;         // h / 3 (0 or 1)
            unsigned hm = h - h3 * 3u;
            unsigned w3 = (w * 171u) >> 9;         // w / 3
            unsigned wm = w - w3 * 3u;
            unsigned src = ((hm | wm) == 0u) ? (h3 * 64u + w3) : 255u; // <128 or 255
            packed |= src << (8 * j);
        }
        tab[p] = packed;
    }
    __syncthreads();

    vfloat4* op = reinterpret_cast<vfloat4*>(out) + bc * PLANE_OUT4;

    auto emit = [&](int q) {
        unsigned g      = ((unsigned)q * 58868u) >> 24;  // q / 285
        unsigned p      = (unsigned)q - g * 285u;
        unsigned xbase  = g << 7;                        // group's 128-float x chunk
        unsigned packed = tab[p];
        vfloat4 v;
#pragma unroll
        for (int j = 0; j < 4; ++j) {
            unsigned b = (packed >> (8 * j)) & 255u;
            float val  = xs[(xbase + b) & (PLANE_IN - 1)]; // always in-bounds
            v[j] = (b != 255u) ? val : 0.0f;               // cndmask, no branch
        }
        __builtin_nontemporal_store(v, op + q);            // nt: no L2 alloc/RFO
    };

#pragma unroll 4
    for (int k = 0; k < FULL_ITERS; ++k)
        emit(k * BLOCK + t);
    if (t < TAIL)
        emit(FULL_ITERS * BLOCK + t);
}

extern "C" void kernel_launch(void* const* d_in, const int* in_sizes, int n_in,
                              void* d_out, int out_size, void* d_ws, size_t ws_size,
                              hipStream_t stream) {
    const float* x = (const float*)d_in[0];
    // d_in[1] is num_zeros (==2), baked into constants.
    float* out = (float*)d_out;

    ZeroWeave_89601607729830_kernel<<<NPLANES, BLOCK, 0, stream>>>(x, out);
}